// Round 1
// baseline (153.765 us; speedup 1.0000x reference)
//
#include <hip/hip_runtime.h>

#define B_  128
#define N_  16
#define T_  32
#define H_  128
#define NH_ 4
#define L_  544   // (N_+1)*T_

__device__ __forceinline__ float wave_reduce_sum(float v) {
    #pragma unroll
    for (int off = 32; off > 0; off >>= 1) v += __shfl_xor(v, off, 64);
    return v;
}
__device__ __forceinline__ float wave_reduce_max(float v) {
    #pragma unroll
    for (int off = 32; off > 0; off >>= 1) v = fmaxf(v, __shfl_xor(v, off, 64));
    return v;
}

// Kernel 1: one block per (batch, head-pair). Computes qk for its 2 heads,
// scores S over all 544 kv rows, softmax, writes A and wctx to workspace.
__global__ __launch_bounds__(256) void attn_kernel(
    const float* __restrict__ node_enc, const float* __restrict__ neigh_enc,
    const int* __restrict__ attn_mask, const int* __restrict__ cts_p,
    const float* __restrict__ w_qs, const float* __restrict__ w_ks,
    float* __restrict__ A_ws, float* __restrict__ wctx_ws)
{
    const int bid  = blockIdx.x;
    const int b    = bid >> 1;
    const int pair = bid & 1;
    const int n0   = pair * 2;         // heads n0, n0+1
    const int t    = threadIdx.x;
    const int cts  = cts_p[0];

    __shared__ __align__(16) float q_sh[H_];
    __shared__ __align__(16) float qs_sh[2][H_];
    __shared__ __align__(16) float qk_sh[2][H_];
    __shared__ __align__(16) float S_sh[2][L_ + 4];
    __shared__ float red_sh[2][2];

    // P0: load q = node_enc[b, cts, :]
    if (t < H_) q_sh[t] = node_enc[b * (T_ * H_) + cts * H_ + t];
    __syncthreads();

    // P1: q_s[g][d] = sum_h q[h] * w_qs[n0+g][h][d]   (coalesced over d)
    {
        int g = t >> 7, d = t & 127;
        const float* w = w_qs + (n0 + g) * (H_ * H_) + d;
        float acc = 0.f;
        #pragma unroll 8
        for (int h = 0; h < H_; ++h) acc += q_sh[h] * w[h * H_];
        qs_sh[g][d] = acc;
    }
    __syncthreads();

    // P2: qk[g][h] = sum_d w_ks[n0+g][h][d] * q_s[g][d]
    {
        int g = t >> 7, h = t & 127;
        const float4* w = (const float4*)(w_ks + (n0 + g) * (H_ * H_) + h * H_);
        const float* qs = qs_sh[g];
        float acc = 0.f;
        #pragma unroll 8
        for (int d4 = 0; d4 < H_ / 4; ++d4) {
            float4 v = w[d4];
            acc += v.x * qs[d4 * 4] + v.y * qs[d4 * 4 + 1]
                 + v.z * qs[d4 * 4 + 2] + v.w * qs[d4 * 4 + 3];
        }
        qk_sh[g][h] = acc;
    }
    __syncthreads();

    // P3: scores. Each thread handles rows l = t, t+256, t+512(<544).
    const float scale = 0.08838834764831845f; // 1/sqrt(128)
    for (int l = t; l < L_; l += 256) {
        const float* rowp = (l < T_)
            ? node_enc  + (size_t)b * (T_ * H_) + l * H_
            : neigh_enc + (size_t)b * (N_ * T_ * H_) + (l - T_) * H_;
        const float4* row = (const float4*)rowp;
        float a0 = 0.f, a1 = 0.f;
        #pragma unroll
        for (int h4 = 0; h4 < H_ / 4; ++h4) {
            float4 v = row[h4];
            int h = h4 * 4;
            a0 += v.x * qk_sh[0][h] + v.y * qk_sh[0][h + 1]
                + v.z * qk_sh[0][h + 2] + v.w * qk_sh[0][h + 3];
            a1 += v.x * qk_sh[1][h] + v.y * qk_sh[1][h + 1]
                + v.z * qk_sh[1][h + 2] + v.w * qk_sh[1][h + 3];
        }
        int m = attn_mask[b * L_ + l];
        S_sh[0][l] = m ? -__builtin_inff() : a0 * scale;
        S_sh[1][l] = m ? -__builtin_inff() : a1 * scale;
    }
    __syncthreads();

    // P4: softmax per head. Threads [0,128) -> head 0, [128,256) -> head 1.
    {
        int g = t >> 7, j = t & 127;
        int wv = (t >> 6) & 1; // wave index within head group
        float m = -__builtin_inff();
        for (int l = j; l < L_; l += 128) m = fmaxf(m, S_sh[g][l]);
        m = wave_reduce_max(m);
        if ((t & 63) == 0) red_sh[g][wv] = m;
        __syncthreads();
        float mfin = fmaxf(red_sh[g][0], red_sh[g][1]);
        float s = 0.f;
        for (int l = j; l < L_; l += 128) {
            float e = __expf(S_sh[g][l] - mfin);
            S_sh[g][l] = e;
            s += e;
        }
        s = wave_reduce_sum(s);
        __syncthreads();
        if ((t & 63) == 0) red_sh[g][wv] = s;
        __syncthreads();
        float inv = 1.0f / (red_sh[g][0] + red_sh[g][1]);
        for (int l = j; l < L_; l += 128) {
            float a = S_sh[g][l] * inv;
            S_sh[g][l] = a;
            A_ws[(size_t)(n0 + g) * (B_ * L_) + b * L_ + l] = a;
        }
    }
    __syncthreads();

    // P5: wctx[g][h] = sum_l A[g][l] * kv[b][l][h]  (coalesced over h)
    {
        int g = t >> 7, h = t & 127;
        const float* As = S_sh[g];
        float acc = 0.f;
        const float* base0 = node_enc + (size_t)b * (T_ * H_) + h;
        #pragma unroll 8
        for (int l = 0; l < T_; ++l) acc += As[l] * base0[l * H_];
        const float* base1 = neigh_enc + (size_t)b * (N_ * T_ * H_) + h;
        #pragma unroll 8
        for (int l = 0; l < L_ - T_; ++l) acc += As[T_ + l] * base1[l * H_];
        wctx_ws[(size_t)(n0 + g) * (B_ * H_) + b * H_ + h] = acc;
    }
}

// Kernel 2: one block per batch. slf_attn, ctx = wctx @ w_vs, projection,
// residual, LayerNorm.
__global__ __launch_bounds__(256) void finish_kernel(
    const float* __restrict__ node_enc, const int* __restrict__ cts_p,
    const float* __restrict__ w_vs, const float* __restrict__ prj_w,
    const float* __restrict__ prj_b, const float* __restrict__ ln_gamma,
    const float* __restrict__ ln_beta, const float* __restrict__ A_ws,
    const float* __restrict__ wctx_ws, float* __restrict__ d_out)
{
    const int b = blockIdx.x;
    const int t = threadIdx.x;
    __shared__ __align__(16) float wctx_sh[NH_ * H_];
    __shared__ __align__(16) float ctx_sh[NH_ * H_];
    __shared__ __align__(16) float part_sh[256];
    __shared__ __align__(16) float x_sh[H_];
    __shared__ float stat_sh[2];

    // slf_attn[b, 0, l] = sum_n A[n][b][l]
    float* slf = d_out + B_ * H_;
    for (int l = t; l < L_; l += 256) {
        float s = 0.f;
        #pragma unroll
        for (int n = 0; n < NH_; ++n) s += A_ws[(size_t)n * (B_ * L_) + b * L_ + l];
        slf[b * L_ + l] = s;
    }
    // load wctx for all 4 heads
    for (int idx = t; idx < NH_ * H_; idx += 256) {
        int n = idx >> 7, h = idx & 127;
        wctx_sh[idx] = wctx_ws[(size_t)n * (B_ * H_) + b * H_ + h];
    }
    __syncthreads();
    // ctx[n][d] = sum_h wctx[n][h] * w_vs[n][h][d]   (coalesced over d)
    for (int idx = t; idx < NH_ * H_; idx += 256) {
        int n = idx >> 7, d = idx & 127;
        const float* w  = w_vs + (size_t)n * (H_ * H_) + d;
        const float* wc = wctx_sh + n * H_;
        float acc = 0.f;
        #pragma unroll 8
        for (int h = 0; h < H_; ++h) acc += wc[h] * w[h * H_];
        ctx_sh[idx] = acc;
    }
    __syncthreads();
    // proj[j] = sum_c cat[c] * prj_w[j][c]; 2 threads per j
    {
        int j = t >> 1, half = t & 1;
        const float4* w = (const float4*)(prj_w + (size_t)j * (NH_ * H_) + half * 256);
        const float4* c = (const float4*)(ctx_sh + half * 256);
        float acc = 0.f;
        #pragma unroll 8
        for (int i = 0; i < 64; ++i) {
            float4 wv = w[i]; float4 cv = c[i];
            acc += wv.x * cv.x + wv.y * cv.y + wv.z * cv.z + wv.w * cv.w;
        }
        part_sh[t] = acc;
    }
    __syncthreads();
    const int cts = cts_p[0];
    if (t < H_) {
        float x = part_sh[2 * t] + part_sh[2 * t + 1] + prj_b[t]
                + node_enc[(size_t)b * (T_ * H_) + cts * H_ + t];
        x_sh[t] = x;
    }
    __syncthreads();
    if (t < 64) {
        float v0 = x_sh[t], v1 = x_sh[t + 64];
        float s1 = v0 + v1;
        float s2 = v0 * v0 + v1 * v1;
        s1 = wave_reduce_sum(s1);
        s2 = wave_reduce_sum(s2);
        if (t == 0) {
            float mean = s1 / (float)H_;
            float var  = s2 / (float)H_ - mean * mean;
            stat_sh[0] = mean;
            stat_sh[1] = rsqrtf(var + 1e-6f);
        }
    }
    __syncthreads();
    if (t < H_) {
        float y = (x_sh[t] - stat_sh[0]) * stat_sh[1] * ln_gamma[t] + ln_beta[t];
        d_out[b * H_ + t] = y;
    }
}

extern "C" void kernel_launch(void* const* d_in, const int* in_sizes, int n_in,
                              void* d_out, int out_size, void* d_ws, size_t ws_size,
                              hipStream_t stream) {
    const float* node_enc  = (const float*)d_in[0];
    const float* neigh_enc = (const float*)d_in[1];
    const int*   attn_mask = (const int*)d_in[2];
    const int*   cts       = (const int*)d_in[3];
    const float* w_qs      = (const float*)d_in[4];
    const float* w_ks      = (const float*)d_in[5];
    const float* w_vs      = (const float*)d_in[6];
    const float* prj_w     = (const float*)d_in[7];
    const float* prj_b     = (const float*)d_in[8];
    const float* ln_gamma  = (const float*)d_in[9];
    const float* ln_beta   = (const float*)d_in[10];

    float* A_ws    = (float*)d_ws;                    // NH*B*L floats
    float* wctx_ws = A_ws + (size_t)NH_ * B_ * L_;    // NH*B*H floats

    attn_kernel<<<B_ * 2, 256, 0, stream>>>(node_enc, neigh_enc, attn_mask, cts,
                                            w_qs, w_ks, A_ws, wctx_ws);
    finish_kernel<<<B_, 256, 0, stream>>>(node_enc, cts, w_vs, prj_w, prj_b,
                                          ln_gamma, ln_beta, A_ws, wctx_ws,
                                          (float*)d_out);
}

// Round 2
// 129.710 us; speedup vs baseline: 1.1855x; 1.1855x over previous
//
#include <hip/hip_runtime.h>

#define B_  128
#define N_  16
#define T_  32
#define H_  128
#define NH_ 4
#define L_  544   // (N_+1)*T_
#define CH  64    // kv rows per chunk
#define NC  9     // ceil(544/64)

// ---------------- K1: qk[n][b][h] = w_ks[n]·(q[b]·w_qs[n]) ----------------
__global__ __launch_bounds__(256) void qk_kernel(
    const float* __restrict__ node_enc, const int* __restrict__ cts_p,
    const float* __restrict__ w_qs, const float* __restrict__ w_ks,
    float* __restrict__ qk_ws)
{
    const int blk = blockIdx.x;
    const int b = blk & 127, n = blk >> 7;
    const int t = threadIdx.x;
    __shared__ float q_sh[H_];
    __shared__ float ps[256];
    __shared__ float qs_sh[H_];

    if (t < H_) q_sh[t] = node_enc[(size_t)b*T_*H_ + cts_p[0]*H_ + t];
    __syncthreads();
    {   // q_s[d] = sum_h q[h]*w_qs[n][h][d]; 2 threads per d (h split)
        int d = t & 127, half = t >> 7;
        const float* w  = w_qs + (size_t)n*H_*H_ + (half*64)*H_ + d;
        const float* qh = q_sh + half*64;
        float acc = 0.f;
        #pragma unroll 8
        for (int h = 0; h < 64; ++h) acc += qh[h] * w[h*H_];
        ps[t] = acc;
    }
    __syncthreads();
    if (t < H_) qs_sh[t] = ps[t] + ps[t+128];
    __syncthreads();
    {   // qk[h] = sum_d w_ks[n][h][d]*q_s[d]; 2 threads per h (d split)
        int h = t & 127, half = t >> 7;
        const float4* w  = (const float4*)(w_ks + (size_t)n*H_*H_ + h*H_ + half*64);
        const float4* qs = (const float4*)(qs_sh + half*64);
        float acc = 0.f;
        #pragma unroll
        for (int i = 0; i < 16; ++i) {
            float4 wv = w[i], qv = qs[i];
            acc += wv.x*qv.x + wv.y*qv.y + wv.z*qv.z + wv.w*qv.w;
        }
        ps[t] = acc;
    }
    __syncthreads();
    if (t < H_) qk_ws[(b*NH_ + n)*H_ + t] = ps[t] + ps[t+128];
}

// ---- K2: single kv pass: scores + chunk-local softmax + partial wctx ----
__global__ __launch_bounds__(256) void attn_main_kernel(
    const float* __restrict__ node_enc, const float* __restrict__ neigh_enc,
    const int* __restrict__ attn_mask, const float* __restrict__ qk_ws,
    float* __restrict__ S_ws, float* __restrict__ wpart_ws,
    float* __restrict__ stats_ws)
{
    const int blk = blockIdx.x;
    const int b = blk / NC, c = blk % NC;
    const int t = threadIdx.x;
    const int l0 = c * CH;
    const int R  = min(CH, L_ - l0);   // 64, last chunk 32

    __shared__ __align__(16) float kv_sh[CH*132];  // +4 pad per row
    __shared__ __align__(16) float qk_sh[4*132];
    __shared__ float S_sh[CH*5];
    __shared__ float P_sh[CH*6];
    __shared__ int   msk_sh[CH];

    for (int j = t; j < 4*H_; j += 256) {
        int g = j >> 7, h = j & 127;
        qk_sh[g*132 + h] = qk_ws[(b*NH_ + g)*H_ + h];
    }
    if (t < R) msk_sh[t] = attn_mask[b*L_ + l0 + t];
    for (int j = t; j < R*32; j += 256) {
        int r = j >> 5, cc = j & 31;
        int l = l0 + r;
        const float* rowp = (l < T_)
            ? node_enc  + (size_t)b*T_*H_ + l*H_
            : neigh_enc + (size_t)b*N_*T_*H_ + (size_t)(l - T_)*H_;
        float4 v = ((const float4*)rowp)[cc];
        *((float4*)(kv_sh + r*132 + cc*4)) = v;
    }
    __syncthreads();

    // scores: thread (r,g), r=t>>2, g=t&3
    {
        int r = t >> 2, g = t & 3;
        float S = -INFINITY;
        if (r < R) {
            const float4* kvv = (const float4*)(kv_sh + r*132);
            const float4* qv  = (const float4*)(qk_sh + g*132);
            float acc = 0.f;
            #pragma unroll
            for (int i = 0; i < 32; ++i) {
                float4 a = kvv[i], q = qv[i];
                acc += a.x*q.x + a.y*q.y + a.z*q.z + a.w*q.w;
            }
            S = msk_sh[r] ? -INFINITY : acc * 0.08838834764831845f;
            S_ws[((size_t)b*L_ + l0 + r)*NH_ + g] = S;
        }
        S_sh[r*5 + g] = S;
    }
    __syncthreads();

    // chunk-local softmax stats per head: wave w handles head w
    {
        int w = t >> 6, lane = t & 63;
        float v = S_sh[lane*5 + w];
        float m = v;
        #pragma unroll
        for (int off = 32; off > 0; off >>= 1) m = fmaxf(m, __shfl_xor(m, off, 64));
        m = fmaxf(m, -1e30f);                    // guard fully-masked chunk
        float p = __expf(v - m);                 // v=-inf -> 0
        P_sh[lane*6 + w] = p;
        float s = p;
        #pragma unroll
        for (int off = 32; off > 0; off >>= 1) s += __shfl_xor(s, off, 64);
        if (lane == 0) {
            stats_ws[((b*NC + c)*NH_ + w)*2 + 0] = m;
            stats_ws[((b*NC + c)*NH_ + w)*2 + 1] = s;
        }
    }
    __syncthreads();

    // partial wctx from the SAME LDS kv copy (no 2nd HBM pass)
    {
        int h = t & 127, gp = t >> 7;   // gp=0 -> heads 0,1; gp=1 -> heads 2,3
        float acc0 = 0.f, acc1 = 0.f;
        #pragma unroll 4
        for (int r = 0; r < R; ++r) {
            float  kvv = kv_sh[r*132 + h];
            float2 p = *((const float2*)(P_sh + r*6 + gp*2));
            acc0 += p.x * kvv;
            acc1 += p.y * kvv;
        }
        float* wp = wpart_ws + (size_t)(b*NC + c)*NH_*H_;
        wp[(gp*2+0)*H_ + h] = acc0;
        wp[(gp*2+1)*H_ + h] = acc1;
    }
}

// ---- K3: combine stats, slf_attn, wctx->ctx->proj->residual->LayerNorm ----
__global__ __launch_bounds__(512) void finish_kernel(
    const float* __restrict__ node_enc, const int* __restrict__ cts_p,
    const float* __restrict__ w_vs, const float* __restrict__ prj_w,
    const float* __restrict__ prj_b, const float* __restrict__ ln_gamma,
    const float* __restrict__ ln_beta, const float* __restrict__ S_ws,
    const float* __restrict__ wpart_ws, const float* __restrict__ stats_ws,
    float* __restrict__ d_out)
{
    const int b = blockIdx.x, t = threadIdx.x;
    __shared__ float stats_sh[NC*NH_*2];
    __shared__ float m_sh[NH_], inv_sh[NH_];
    __shared__ float scale_sh[NC*NH_];
    __shared__ __align__(16) float wctx_sh[NH_*H_];
    __shared__ __align__(16) float cat_sh[NH_*H_];
    __shared__ float part_sh[512];
    __shared__ float x_sh[H_];
    __shared__ float st2[2];

    if (t < NC*NH_*2) stats_sh[t] = stats_ws[b*NC*NH_*2 + t];
    __syncthreads();
    if (t < NH_) {
        float m = -INFINITY;
        #pragma unroll
        for (int c = 0; c < NC; ++c) m = fmaxf(m, stats_sh[(c*NH_+t)*2]);
        float s = 0.f;
        #pragma unroll
        for (int c = 0; c < NC; ++c)
            s += stats_sh[(c*NH_+t)*2+1] * __expf(stats_sh[(c*NH_+t)*2] - m);
        m_sh[t] = m;
        inv_sh[t] = 1.0f / s;
    }
    __syncthreads();
    if (t < NC*NH_) {
        int c = t >> 2, n = t & 3;
        scale_sh[t] = __expf(stats_sh[(c*NH_+n)*2] - m_sh[n]) * inv_sh[n];
    }
    __syncthreads();

    // slf_attn[b,0,l] = sum_n exp(S-m)/sum
    {
        float m0 = m_sh[0], m1 = m_sh[1], m2 = m_sh[2], m3 = m_sh[3];
        float i0 = inv_sh[0], i1 = inv_sh[1], i2 = inv_sh[2], i3 = inv_sh[3];
        float* slf = d_out + B_*H_ + b*L_;
        const float4* Sr = (const float4*)(S_ws + (size_t)b*L_*NH_);
        for (int l = t; l < L_; l += 512) {
            float4 s4 = Sr[l];
            slf[l] = __expf(s4.x - m0)*i0 + __expf(s4.y - m1)*i1
                   + __expf(s4.z - m2)*i2 + __expf(s4.w - m3)*i3;
        }
    }
    // wctx: rescale-combine partials (512 values, 1/thread)
    {
        int n = t >> 7;
        const float* wp = wpart_ws + (size_t)b*NC*NH_*H_;
        float acc = 0.f;
        #pragma unroll
        for (int c = 0; c < NC; ++c)
            acc += wp[c*NH_*H_ + t] * scale_sh[c*NH_ + n];
        wctx_sh[t] = acc;
    }
    __syncthreads();
    // ctx[n][d] = sum_h wctx[n][h]*w_vs[n][h][d]  -> cat layout [n*128+d]
    {
        int n = t >> 7, d = t & 127;
        const float* w  = w_vs + (size_t)n*H_*H_ + d;
        const float* wc = wctx_sh + n*H_;
        float acc = 0.f;
        #pragma unroll 8
        for (int h = 0; h < H_; ++h) acc += wc[h] * w[h*H_];
        cat_sh[t] = acc;
    }
    __syncthreads();
    // proj: 4 threads per output j
    {
        int j = t >> 2, q = t & 3;
        const float4* w  = (const float4*)(prj_w + (size_t)j*(NH_*H_) + q*128);
        const float4* cc = (const float4*)(cat_sh + q*128);
        float acc = 0.f;
        #pragma unroll
        for (int i = 0; i < 32; ++i) {
            float4 wv = w[i], cv = cc[i];
            acc += wv.x*cv.x + wv.y*cv.y + wv.z*cv.z + wv.w*cv.w;
        }
        part_sh[t] = acc;
    }
    __syncthreads();
    if (t < H_) {
        float x = part_sh[4*t] + part_sh[4*t+1] + part_sh[4*t+2] + part_sh[4*t+3]
                + prj_b[t] + node_enc[(size_t)b*T_*H_ + cts_p[0]*H_ + t];
        x_sh[t] = x;
    }
    __syncthreads();
    if (t < 64) {
        float v0 = x_sh[t], v1 = x_sh[t+64];
        float s1 = v0 + v1, s2 = v0*v0 + v1*v1;
        #pragma unroll
        for (int off = 32; off > 0; off >>= 1) {
            s1 += __shfl_xor(s1, off, 64);
            s2 += __shfl_xor(s2, off, 64);
        }
        if (t == 0) {
            float mean = s1 / (float)H_;
            float var  = s2 / (float)H_ - mean*mean;
            st2[0] = mean;
            st2[1] = rsqrtf(var + 1e-6f);
        }
    }
    __syncthreads();
    if (t < H_)
        d_out[b*H_ + t] = (x_sh[t] - st2[0]) * st2[1] * ln_gamma[t] + ln_beta[t];
}

extern "C" void kernel_launch(void* const* d_in, const int* in_sizes, int n_in,
                              void* d_out, int out_size, void* d_ws, size_t ws_size,
                              hipStream_t stream) {
    const float* node_enc  = (const float*)d_in[0];
    const float* neigh_enc = (const float*)d_in[1];
    const int*   attn_mask = (const int*)d_in[2];
    const int*   cts       = (const int*)d_in[3];
    const float* w_qs      = (const float*)d_in[4];
    const float* w_ks      = (const float*)d_in[5];
    const float* w_vs      = (const float*)d_in[6];
    const float* prj_w     = (const float*)d_in[7];
    const float* prj_b     = (const float*)d_in[8];
    const float* ln_gamma  = (const float*)d_in[9];
    const float* ln_beta   = (const float*)d_in[10];

    float* qk_ws    = (float*)d_ws;                       // B*NH*H   = 65536
    float* S_ws     = qk_ws + (size_t)B_*NH_*H_;          // B*L*NH   = 278528
    float* wpart_ws = S_ws + (size_t)B_*L_*NH_;           // B*NC*NH*H= 589824
    float* stats_ws = wpart_ws + (size_t)B_*NC*NH_*H_;    // B*NC*NH*2= 9216

    qk_kernel<<<B_*NH_, 256, 0, stream>>>(node_enc, cts, w_qs, w_ks, qk_ws);
    attn_main_kernel<<<B_*NC, 256, 0, stream>>>(node_enc, neigh_enc, attn_mask,
                                                qk_ws, S_ws, wpart_ws, stats_ws);
    finish_kernel<<<B_, 512, 0, stream>>>(node_enc, cts, w_vs, prj_w, prj_b,
                                          ln_gamma, ln_beta, S_ws, wpart_ws,
                                          stats_ws, (float*)d_out);
}